// Round 7
// baseline (9988.901 us; speedup 1.0000x reference)
//
#include <hip/hip_runtime.h>

#define NWG 128
#define TSTEPS 512

typedef __attribute__((ext_vector_type(8))) short short8;
typedef __attribute__((ext_vector_type(4))) float f32x4;
typedef __attribute__((ext_vector_type(4))) int int4v;

// ---- LDS offsets (bytes) ----
#define T0_OFF   0            // [z8|r8] rows, K=1536, 48 ksteps * 1KB = 48 KB
#define T1_OFF   49152        // [o8|c8] rows, K=1536 (c zero for k>=512), 48 KB
#define T2_OFF   98304        // [c8|0] rows, rc-range K=1024, 32 ksteps = 32 KB
#define ZBUF_OFF 135168       // f32 arrays padded to stride 65
#define OBUF_OFF 137248
#define XCB_OFF  139328
#define CST_OFF  141408
#define RCS_OFF  143488
#define HST_OFF  145568
#define BIAS_OFF 147648       // [32] f32
#define LDS_BYTES 147776
#define PAD 65

// Replica geometry: each replica of hbuf/rcbuf is [2][64][1024] bf16 = 256 KB.
#define REP_SHORTS 131072     // 262144 bytes / 2

__device__ inline unsigned short f2bf(float f) {
  unsigned int b = __float_as_uint(f);
  return (unsigned short)((b + 0x7FFFu + ((b >> 16) & 1u)) >> 16);  // RNE
}
__device__ inline float sigm(float x) { return 1.f / (1.f + __expf(-x)); }
__device__ inline float tanh_f(float x) { float e = __expf(2.f * x); return 1.f - 2.f / (e + 1.f); }

// packed f32->bf16 (RNE, same rounding as f2bf): 8 floats -> short8 in 4 insts
__device__ inline short8 cvt8(f32x4 a, f32x4 b) {
  int w0, w1, w2, w3;
  asm("v_cvt_pk_bf16_f32 %0, %1, %2" : "=v"(w0) : "v"(a[0]), "v"(a[1]));
  asm("v_cvt_pk_bf16_f32 %0, %1, %2" : "=v"(w1) : "v"(a[2]), "v"(a[3]));
  asm("v_cvt_pk_bf16_f32 %0, %1, %2" : "=v"(w2) : "v"(b[0]), "v"(b[1]));
  asm("v_cvt_pk_bf16_f32 %0, %1, %2" : "=v"(w3) : "v"(b[2]), "v"(b[3]));
  int4v r = {w0, w1, w2, w3};
  return __builtin_bit_cast(short8, r);
}

// ---- fine-grained coherent (LLC-level) helpers: the PROVEN exchange path ----
__device__ inline void cstore16(void* p, short8 v) {
  asm volatile("global_store_dwordx4 %0, %1, off sc0 sc1" :: "v"(p), "v"(v) : "memory");
}
__device__ inline void cstore4(void* p, int v) {
  asm volatile("global_store_dword %0, %1, off sc0 sc1" :: "v"(p), "v"(v) : "memory");
}
__device__ inline int cload4(const void* p) {
  int v;
  asm volatile("global_load_dword %0, %1, off sc0 sc1\n\ts_waitcnt vmcnt(0)"
               : "=&v"(v) : "v"(p) : "memory");
  return v;
}
__device__ inline void vmdrain()  { asm volatile("s_waitcnt vmcnt(0)"  ::: "memory"); }
__device__ inline void vmwait16() { asm volatile("s_waitcnt vmcnt(16)" ::: "memory"); }

// 16 coherent 16B loads, stride 64B, NO wait (caller waits + sched_barrier).
__device__ inline void cload16_issue(const unsigned short* p, short8* a) {
  asm volatile(
    "global_load_dwordx4 %0,  %16, off sc0 sc1\n\t"
    "global_load_dwordx4 %1,  %16, off offset:64 sc0 sc1\n\t"
    "global_load_dwordx4 %2,  %16, off offset:128 sc0 sc1\n\t"
    "global_load_dwordx4 %3,  %16, off offset:192 sc0 sc1\n\t"
    "global_load_dwordx4 %4,  %16, off offset:256 sc0 sc1\n\t"
    "global_load_dwordx4 %5,  %16, off offset:320 sc0 sc1\n\t"
    "global_load_dwordx4 %6,  %16, off offset:384 sc0 sc1\n\t"
    "global_load_dwordx4 %7,  %16, off offset:448 sc0 sc1\n\t"
    "global_load_dwordx4 %8,  %16, off offset:512 sc0 sc1\n\t"
    "global_load_dwordx4 %9,  %16, off offset:576 sc0 sc1\n\t"
    "global_load_dwordx4 %10, %16, off offset:640 sc0 sc1\n\t"
    "global_load_dwordx4 %11, %16, off offset:704 sc0 sc1\n\t"
    "global_load_dwordx4 %12, %16, off offset:768 sc0 sc1\n\t"
    "global_load_dwordx4 %13, %16, off offset:832 sc0 sc1\n\t"
    "global_load_dwordx4 %14, %16, off offset:896 sc0 sc1\n\t"
    "global_load_dwordx4 %15, %16, off offset:960 sc0 sc1"
    : "=&v"(a[0]), "=&v"(a[1]), "=&v"(a[2]), "=&v"(a[3]),
      "=&v"(a[4]), "=&v"(a[5]), "=&v"(a[6]), "=&v"(a[7]),
      "=&v"(a[8]), "=&v"(a[9]), "=&v"(a[10]), "=&v"(a[11]),
      "=&v"(a[12]), "=&v"(a[13]), "=&v"(a[14]), "=&v"(a[15])
    : "v"(p)
    : "memory");
}

// 16 normal (cached) 16B f32 loads, stride 128B, NO wait (read-only x input).
__device__ inline void gload16_issue_s128(const float* p, f32x4* a) {
  asm volatile(
    "global_load_dwordx4 %0,  %16, off\n\t"
    "global_load_dwordx4 %1,  %16, off offset:128\n\t"
    "global_load_dwordx4 %2,  %16, off offset:256\n\t"
    "global_load_dwordx4 %3,  %16, off offset:384\n\t"
    "global_load_dwordx4 %4,  %16, off offset:512\n\t"
    "global_load_dwordx4 %5,  %16, off offset:640\n\t"
    "global_load_dwordx4 %6,  %16, off offset:768\n\t"
    "global_load_dwordx4 %7,  %16, off offset:896\n\t"
    "global_load_dwordx4 %8,  %16, off offset:1024\n\t"
    "global_load_dwordx4 %9,  %16, off offset:1152\n\t"
    "global_load_dwordx4 %10, %16, off offset:1280\n\t"
    "global_load_dwordx4 %11, %16, off offset:1408\n\t"
    "global_load_dwordx4 %12, %16, off offset:1536\n\t"
    "global_load_dwordx4 %13, %16, off offset:1664\n\t"
    "global_load_dwordx4 %14, %16, off offset:1792\n\t"
    "global_load_dwordx4 %15, %16, off offset:1920"
    : "=&v"(a[0]), "=&v"(a[1]), "=&v"(a[2]), "=&v"(a[3]),
      "=&v"(a[4]), "=&v"(a[5]), "=&v"(a[6]), "=&v"(a[7]),
      "=&v"(a[8]), "=&v"(a[9]), "=&v"(a[10]), "=&v"(a[11]),
      "=&v"(a[12]), "=&v"(a[13]), "=&v"(a[14]), "=&v"(a[15])
    : "v"(p)
    : "memory");
}

// R = replica count for the exchange buffers (1 = byte-identical round-2 path).
// Producers write all R replicas; consumer WG reads replica (wg & (R-1)).
// Purpose: cut same-line readers at the LLC from 128 to 128/R.
template<int R>
__global__ void __launch_bounds__(256, 1) lmgru_kernel(
    const float* __restrict__ x,
    const float* __restrict__ Wz, const float* __restrict__ bz,
    const float* __restrict__ Wr, const float* __restrict__ br,
    const float* __restrict__ Wc, const float* __restrict__ bc,
    const float* __restrict__ Wo, const float* __restrict__ bo,
    const float* __restrict__ fcw, const float* __restrict__ fcb,
    float* __restrict__ out, char* __restrict__ ws)
{
  extern __shared__ char lds[];
  const int tid  = threadIdx.x;
  const int wg   = blockIdx.x;
  const int lane = tid & 63;
  const int q    = tid >> 6;          // wave id 0..3 == M-tile

  // ---- workspace layout (R-parameterized) ----
  unsigned short* hbuf0  = (unsigned short*)ws;                       // R x [2][64][1024]
  unsigned short* rcbuf0 = (unsigned short*)(ws + (size_t)R * 262144);
  int*   hflag  = (int*)(ws + (size_t)2 * R * 262144);                // 128 flags, 64B apart
  int*   rcflag = hflag + 2048;
  float* h32    = (float*)(ws + (size_t)2 * R * 262144 + 65536);      // [64][1024] f32

  float* zbuf = (float*)(lds + ZBUF_OFF);
  float* obuf = (float*)(lds + OBUF_OFF);
  float* xcb  = (float*)(lds + XCB_OFF);
  float* cst  = (float*)(lds + CST_OFF);
  float* rcs  = (float*)(lds + RCS_OFF);
  float* hst  = (float*)(lds + HST_OFF);
  float* bias = (float*)(lds + BIAS_OFF);

  const float* Wg[4] = {Wz, Wr, Wo, Wc};   // n-row layout: [z8 r8 o8 c8]

  // ================= INIT: build fragment-ordered bf16 weights in LDS =================
  for (int it = 0; it < 12; ++it) {
    int slot = tid + 256 * it;               // 3072 slots
    int s = slot >> 6, l = slot & 63;
    int nn = l & 15, kg = (l >> 4) & 3;
    int k = 32 * s + kg * 8;
    int g = (nn < 8) ? 0 : 1;
    const float* src = Wg[g] + (8 * wg + (nn & 7)) * 1536 + k;
    short8 pk;
    #pragma unroll
    for (int j = 0; j < 8; ++j) pk[j] = (short)f2bf(src[j]);
    *(short8*)(lds + T0_OFF + s * 1024 + l * 16) = pk;
  }
  for (int it = 0; it < 12; ++it) {
    int slot = tid + 256 * it;
    int s = slot >> 6, l = slot & 63;
    int nn = l & 15, kg = (l >> 4) & 3;
    int k = 32 * s + kg * 8;
    int g = (nn < 8) ? 2 : 3;
    short8 pk = {};
    if (g == 2 || k < 512) {
      const float* src = Wg[g] + (8 * wg + (nn & 7)) * 1536 + k;
      #pragma unroll
      for (int j = 0; j < 8; ++j) pk[j] = (short)f2bf(src[j]);
    }
    *(short8*)(lds + T1_OFF + s * 1024 + l * 16) = pk;
  }
  for (int it = 0; it < 8; ++it) {
    int slot = tid + 256 * it;               // 2048 slots
    int s = slot >> 6, l = slot & 63;
    int nn = l & 15, kg = (l >> 4) & 3;
    int k = 32 * s + kg * 8;                 // 0..1023
    short8 pk = {};
    if (nn < 8) {
      const float* src = Wc + (8 * wg + nn) * 1536 + 512 + k;
      #pragma unroll
      for (int j = 0; j < 8; ++j) pk[j] = (short)f2bf(src[j]);
    }
    *(short8*)(lds + T2_OFF + s * 1024 + l * 16) = pk;
  }
  if (tid < 32) {
    const float* Bg[4] = {bz, br, bo, bc};
    bias[tid] = Bg[tid >> 3][8 * wg + (tid & 7)];
  }
  for (int i2 = tid; i2 < 8 * PAD; i2 += 256) cst[i2] = 0.f;   // c state = 0
  if (tid < 64) {                            // h_0 = 0 (parity 0), all replicas
    short8 z8 = {};
    #pragma unroll
    for (int r = 0; r < R; ++r)
      cstore16(hbuf0 + r * REP_SHORTS + tid * 1024 + 8 * wg, z8);
  }
  __syncthreads();
  if (tid == 0) {                            // flags: poison(negative) -> 0 releases init
    vmdrain();
    cstore4(hflag + wg * 16, 0);
    cstore4(rcflag + wg * 16, 0);
  }

  const int nn  = lane & 15;             // fragment col (output unit within tile)
  const int kg8 = ((lane >> 4) & 3) * 8; // A-frag k offset within kstep
  const int rbase = ((lane >> 4) & 3) * 4;
  const int brow  = 16 * q + nn;         // this thread's A-row (batch)
  const f32x4 zero4 = {0.f, 0.f, 0.f, 0.f};

  // this WG's read replica
  unsigned short* myh  = hbuf0  + (wg & (R - 1)) * REP_SHORTS;
  unsigned short* myrc = rcbuf0 + (wg & (R - 1)) * REP_SHORTS;

  // ================= RECURRENCE: 2 sync rounds per step =================
  for (int t = 1; t <= TSTEPS; ++t) {
    const int pc = t & 1, pp = (t - 1) & 1;

    // ---------- PHASE 1: z, r, o preacts + Xc, all 64 batches ----------
    // x_t loads (read-only input, normal cached path) BEFORE the flag wait.
    f32x4 xa[16], xb[16];
    {
      const float* xp = x + brow * 262144 + (t - 1) * 512 + kg8;
      gload16_issue_s128(xp, xa);
      gload16_issue_s128(xp + 4, xb);
    }
    if (tid < 128) {
      const int* fp = hflag + tid * 16;
      while (cload4(fp) < t - 1) __builtin_amdgcn_s_sleep(1);
    }
    __syncthreads();
    vmdrain();                                // x data landed (explicit asm wait)
    __builtin_amdgcn_sched_barrier(0);
    short8 axf[16];
    #pragma unroll
    for (int j = 0; j < 16; ++j) axf[j] = cvt8(xa[j], xb[j]);

    // gather h_{t-1} (coherent, own replica) and run x-part MFMAs while it flies
    f32x4 acc0a = zero4, acc0b = zero4, acc1a = zero4, acc1b = zero4;
    const unsigned short* hb = myh + pp * 65536 + brow * 1024;
    short8 ah0[16], ah1[16];
    cload16_issue(hb + kg8, ah0);
    cload16_issue(hb + 512 + kg8, ah1);
    #pragma unroll
    for (int j = 0; j < 16; ++j) {            // s = j : x ksteps
      short8 b0 = *(const short8*)(lds + T0_OFF + j * 1024 + lane * 16);
      short8 b1 = *(const short8*)(lds + T1_OFF + j * 1024 + lane * 16);
      f32x4& A0 = (j & 1) ? acc0b : acc0a;
      f32x4& A1 = (j & 1) ? acc1b : acc1a;
      A0 = __builtin_amdgcn_mfma_f32_16x16x32_bf16(axf[j], b0, A0, 0, 0, 0);
      A1 = __builtin_amdgcn_mfma_f32_16x16x32_bf16(axf[j], b1, A1, 0, 0, 0);
    }
    vmwait16();                               // ah0 (oldest 16) landed
    __builtin_amdgcn_sched_barrier(0);        // rule#18: no MFMA hoist past wait
    #pragma unroll
    for (int j = 0; j < 16; ++j) {            // s = 16+j : h[0:512]
      int s = 16 + j;
      short8 b0 = *(const short8*)(lds + T0_OFF + s * 1024 + lane * 16);
      short8 b1 = *(const short8*)(lds + T1_OFF + s * 1024 + lane * 16);
      f32x4& A0 = (j & 1) ? acc0b : acc0a;
      f32x4& A1 = (j & 1) ? acc1b : acc1a;
      A0 = __builtin_amdgcn_mfma_f32_16x16x32_bf16(ah0[j], b0, A0, 0, 0, 0);
      A1 = __builtin_amdgcn_mfma_f32_16x16x32_bf16(ah0[j], b1, A1, 0, 0, 0);
    }
    vmdrain();
    __builtin_amdgcn_sched_barrier(0);
    #pragma unroll
    for (int j = 0; j < 16; ++j) {            // s = 32+j : h[512:1024]
      int s = 32 + j;
      short8 b0 = *(const short8*)(lds + T0_OFF + s * 1024 + lane * 16);
      short8 b1 = *(const short8*)(lds + T1_OFF + s * 1024 + lane * 16);
      f32x4& A0 = (j & 1) ? acc0b : acc0a;
      f32x4& A1 = (j & 1) ? acc1b : acc1a;
      A0 = __builtin_amdgcn_mfma_f32_16x16x32_bf16(ah1[j], b0, A0, 0, 0, 0);
      A1 = __builtin_amdgcn_mfma_f32_16x16x32_bf16(ah1[j], b1, A1, 0, 0, 0);
    }
    {
      f32x4 acc0 = acc0a + acc0b, acc1 = acc1a + acc1b;
      #pragma unroll
      for (int i = 0; i < 4; ++i) {
        int b = 16 * q + rbase + i;
        float v0 = acc0[i] + bias[nn];        // z or r preact
        float v1 = acc1[i] + bias[16 + nn];   // o preact or Xc(+bias_c)
        if (nn < 8) {
          zbuf[nn * PAD + b] = sigm(v0);
          obuf[nn * PAD + b] = sigm(v1);
        } else {
          int u = nn - 8;
          rcs[u * PAD + b] = sigm(v0) * cst[u * PAD + b];  // r * c_{t-1}
          xcb[u * PAD + b] = v1;                            // Xc + bias_c
        }
      }
    }
    __syncthreads();
    if (tid < 64) {                            // wave 0: pack rc -> all replicas + flag
      short8 pk;
      #pragma unroll
      for (int u = 0; u < 8; ++u) pk[u] = (short)f2bf(rcs[u * PAD + tid]);
      #pragma unroll
      for (int r = 0; r < R; ++r)
        cstore16(rcbuf0 + r * REP_SHORTS + pc * 65536 + tid * 1024 + 8 * wg, pk);
      vmdrain();                               // wave-level: covers all lanes' stores
      if (tid == 0) cstore4(rcflag + wg * 16, t);
    }

    // ---------- PHASE 2: c_tilde, combine, publish h, all 64 batches ----------
    if (tid < 128) {
      const int* fp = rcflag + tid * 16;
      while (cload4(fp) < t) __builtin_amdgcn_s_sleep(1);
    }
    __syncthreads();

    f32x4 acca = zero4, accb = zero4;
    const unsigned short* rb = myrc + pc * 65536 + brow * 1024;
    short8 ar0[16], ar1[16];
    cload16_issue(rb + kg8, ar0);
    cload16_issue(rb + 512 + kg8, ar1);
    vmwait16();
    __builtin_amdgcn_sched_barrier(0);
    #pragma unroll
    for (int j = 0; j < 16; ++j) {
      short8 bf = *(const short8*)(lds + T2_OFF + j * 1024 + lane * 16);
      f32x4& A = (j & 1) ? accb : acca;
      A = __builtin_amdgcn_mfma_f32_16x16x32_bf16(ar0[j], bf, A, 0, 0, 0);
    }
    vmdrain();
    __builtin_amdgcn_sched_barrier(0);
    #pragma unroll
    for (int j = 0; j < 16; ++j) {
      int s = 16 + j;
      short8 bf = *(const short8*)(lds + T2_OFF + s * 1024 + lane * 16);
      f32x4& A = (j & 1) ? accb : acca;
      A = __builtin_amdgcn_mfma_f32_16x16x32_bf16(ar1[j], bf, A, 0, 0, 0);
    }
    if (nn < 8) {
      f32x4 acc = acca + accb;
      #pragma unroll
      for (int i = 0; i < 4; ++i) {
        int b = 16 * q + rbase + i;
        float ct = tanh_f(acc[i] + xcb[nn * PAD + b]);
        float z  = zbuf[nn * PAD + b];
        float cn = z * cst[nn * PAD + b] + (1.f - z) * ct;
        cst[nn * PAD + b] = cn;
        hst[nn * PAD + b] = obuf[nn * PAD + b] * tanh_f(cn);
      }
    }
    __syncthreads();
    if (tid < 64) {                            // wave 0: pack h -> all replicas + flag
      if (t < TSTEPS) {
        short8 pk;
        #pragma unroll
        for (int u = 0; u < 8; ++u) pk[u] = (short)f2bf(hst[u * PAD + tid]);
        #pragma unroll
        for (int r = 0; r < R; ++r)
          cstore16(hbuf0 + r * REP_SHORTS + pc * 65536 + tid * 1024 + 8 * wg, pk);
        vmdrain();
        if (tid == 0) cstore4(hflag + wg * 16, t);
      } else {
        #pragma unroll
        for (int u = 0; u < 8; ++u) h32[tid * 1024 + 8 * wg + u] = hst[u * PAD + tid];
        if (tid == 0)
          __hip_atomic_store(hflag + wg * 16, t, __ATOMIC_RELEASE, __HIP_MEMORY_SCOPE_AGENT);
      }
    }
  }

  // ================= FINAL FC: out = h_T @ fc_w^T + fc_b =================
  if (tid < 128) {
    while (__hip_atomic_load(hflag + tid * 16, __ATOMIC_RELAXED, __HIP_MEMORY_SCOPE_AGENT) < TSTEPS)
      __builtin_amdgcn_s_sleep(1);
  }
  __syncthreads();
  vmdrain();
  __builtin_amdgcn_fence(__ATOMIC_ACQUIRE, "agent");   // proven handoff pattern

  if (wg < 125) {                                // 125 WGs * 8 classes = 1000
    for (int cc = 0; cc < 2; ++cc) {
      int c = 8 * wg + 2 * q + cc;
      const float* wrow = fcw + c * 1024;
      for (int b = 0; b < 64; ++b) {
        const float* hrow = h32 + b * 1024;
        float s = 0.f;
        for (int kk = lane; kk < 1024; kk += 64) s = __builtin_fmaf(hrow[kk], wrow[kk], s);
        #pragma unroll
        for (int off = 32; off; off >>= 1) s += __shfl_xor(s, off);
        if (lane == 0) out[b * 1000 + c] = s + fcb[c];
      }
    }
  }
}

extern "C" void kernel_launch(void* const* d_in, const int* in_sizes, int n_in,
                              void* d_out, int out_size, void* d_ws, size_t ws_size,
                              hipStream_t stream) {
  (void)in_sizes; (void)n_in; (void)out_size;
  const float* x   = (const float*)d_in[0];
  const float* Wz  = (const float*)d_in[1];
  const float* bz  = (const float*)d_in[2];
  const float* Wr  = (const float*)d_in[3];
  const float* br  = (const float*)d_in[4];
  const float* Wc  = (const float*)d_in[5];
  const float* bc  = (const float*)d_in[6];
  const float* Wo  = (const float*)d_in[7];
  const float* bo  = (const float*)d_in[8];
  const float* fcw = (const float*)d_in[9];
  const float* fcb = (const float*)d_in[10];

  // R=8 layout needs 2*8*256KB (buffers) + 64KB (flags) + 256KB (h32) = 4521984 B.
  const size_t NEED8 = (size_t)2 * 8 * 262144 + 65536 + 262144;

  if (ws_size >= NEED8) {
    hipFuncSetAttribute((const void*)lmgru_kernel<8>,
                        hipFuncAttributeMaxDynamicSharedMemorySize, LDS_BYTES);
    hipLaunchKernelGGL(lmgru_kernel<8>, dim3(NWG), dim3(256), LDS_BYTES, stream,
                       x, Wz, bz, Wr, br, Wc, bc, Wo, bo, fcw, fcb,
                       (float*)d_out, (char*)d_ws);
  } else {
    hipFuncSetAttribute((const void*)lmgru_kernel<1>,
                        hipFuncAttributeMaxDynamicSharedMemorySize, LDS_BYTES);
    hipLaunchKernelGGL(lmgru_kernel<1>, dim3(NWG), dim3(256), LDS_BYTES, stream,
                       x, Wz, bz, Wr, br, Wc, bc, Wo, bo, fcw, fcb,
                       (float*)d_out, (char*)d_ws);
  }
}

// Round 8
// 8592.746 us; speedup vs baseline: 1.1625x; 1.1625x over previous
//
#include <hip/hip_runtime.h>

#define NWG 128
#define TSTEPS 512

typedef __attribute__((ext_vector_type(8))) short short8;
typedef __attribute__((ext_vector_type(4))) float f32x4;
typedef __attribute__((ext_vector_type(4))) int int4v;

// ---- LDS offsets (bytes) ----
#define T0_OFF   0            // [z8|r8] rows, K=1536, 48 ksteps * 1KB = 48 KB
#define T1_OFF   49152        // [o8|c8] rows, K=1536 (c zero for k>=512), 48 KB
#define T2_OFF   98304        // [c8|0] rows, rc-range K=1024, 32 ksteps = 32 KB
#define ZBUF_OFF 135168       // f32 arrays padded to stride 65
#define OBUF_OFF 137248
#define XCB_OFF  139328
#define CST_OFF  141408
#define RCS_OFF  143488
#define HST_OFF  145568
#define BIAS_OFF 147648       // [32] f32
#define LDS_BYTES 147776
#define PAD 65

__device__ inline unsigned short f2bf(float f) {
  unsigned int b = __float_as_uint(f);
  return (unsigned short)((b + 0x7FFFu + ((b >> 16) & 1u)) >> 16);  // RNE
}
__device__ inline float sigm(float x) { return 1.f / (1.f + __expf(-x)); }
__device__ inline float tanh_f(float x) { float e = __expf(2.f * x); return 1.f - 2.f / (e + 1.f); }

// packed f32->bf16 (RNE, same rounding as f2bf): 8 floats -> short8 in 4 insts
__device__ inline short8 cvt8(f32x4 a, f32x4 b) {
  int w0, w1, w2, w3;
  asm("v_cvt_pk_bf16_f32 %0, %1, %2" : "=v"(w0) : "v"(a[0]), "v"(a[1]));
  asm("v_cvt_pk_bf16_f32 %0, %1, %2" : "=v"(w1) : "v"(a[2]), "v"(a[3]));
  asm("v_cvt_pk_bf16_f32 %0, %1, %2" : "=v"(w2) : "v"(b[0]), "v"(b[1]));
  asm("v_cvt_pk_bf16_f32 %0, %1, %2" : "=v"(w3) : "v"(b[2]), "v"(b[3]));
  int4v r = {w0, w1, w2, w3};
  return __builtin_bit_cast(short8, r);
}

// ---- fine-grained coherent (LLC-level) access helpers: no wbl2 / no inv ----
__device__ inline void cstore16(void* p, short8 v) {
  asm volatile("global_store_dwordx4 %0, %1, off sc0 sc1" :: "v"(p), "v"(v) : "memory");
}
__device__ inline void cstore4(void* p, int v) {
  asm volatile("global_store_dword %0, %1, off sc0 sc1" :: "v"(p), "v"(v) : "memory");
}
__device__ inline int cload4(const void* p) {
  int v;
  asm volatile("global_load_dword %0, %1, off sc0 sc1\n\ts_waitcnt vmcnt(0)"
               : "=&v"(v) : "v"(p) : "memory");
  return v;
}
__device__ inline void vmdrain() {
  asm volatile("s_waitcnt vmcnt(0)" ::: "memory");
}
__device__ inline void vmwait16() {
  asm volatile("s_waitcnt vmcnt(16)" ::: "memory");
}

// 16 coherent 16B loads, stride 64B, NO wait (caller waits + sched_barrier).
__device__ inline void cload16_issue(const unsigned short* p, short8* a) {
  asm volatile(
    "global_load_dwordx4 %0,  %16, off sc0 sc1\n\t"
    "global_load_dwordx4 %1,  %16, off offset:64 sc0 sc1\n\t"
    "global_load_dwordx4 %2,  %16, off offset:128 sc0 sc1\n\t"
    "global_load_dwordx4 %3,  %16, off offset:192 sc0 sc1\n\t"
    "global_load_dwordx4 %4,  %16, off offset:256 sc0 sc1\n\t"
    "global_load_dwordx4 %5,  %16, off offset:320 sc0 sc1\n\t"
    "global_load_dwordx4 %6,  %16, off offset:384 sc0 sc1\n\t"
    "global_load_dwordx4 %7,  %16, off offset:448 sc0 sc1\n\t"
    "global_load_dwordx4 %8,  %16, off offset:512 sc0 sc1\n\t"
    "global_load_dwordx4 %9,  %16, off offset:576 sc0 sc1\n\t"
    "global_load_dwordx4 %10, %16, off offset:640 sc0 sc1\n\t"
    "global_load_dwordx4 %11, %16, off offset:704 sc0 sc1\n\t"
    "global_load_dwordx4 %12, %16, off offset:768 sc0 sc1\n\t"
    "global_load_dwordx4 %13, %16, off offset:832 sc0 sc1\n\t"
    "global_load_dwordx4 %14, %16, off offset:896 sc0 sc1\n\t"
    "global_load_dwordx4 %15, %16, off offset:960 sc0 sc1"
    : "=&v"(a[0]), "=&v"(a[1]), "=&v"(a[2]), "=&v"(a[3]),
      "=&v"(a[4]), "=&v"(a[5]), "=&v"(a[6]), "=&v"(a[7]),
      "=&v"(a[8]), "=&v"(a[9]), "=&v"(a[10]), "=&v"(a[11]),
      "=&v"(a[12]), "=&v"(a[13]), "=&v"(a[14]), "=&v"(a[15])
    : "v"(p)
    : "memory");
}

// 16 normal (cached) 16B f32 loads, stride 128B, NO wait.
__device__ inline void gload16_issue_s128(const float* p, f32x4* a) {
  asm volatile(
    "global_load_dwordx4 %0,  %16, off\n\t"
    "global_load_dwordx4 %1,  %16, off offset:128\n\t"
    "global_load_dwordx4 %2,  %16, off offset:256\n\t"
    "global_load_dwordx4 %3,  %16, off offset:384\n\t"
    "global_load_dwordx4 %4,  %16, off offset:512\n\t"
    "global_load_dwordx4 %5,  %16, off offset:640\n\t"
    "global_load_dwordx4 %6,  %16, off offset:768\n\t"
    "global_load_dwordx4 %7,  %16, off offset:896\n\t"
    "global_load_dwordx4 %8,  %16, off offset:1024\n\t"
    "global_load_dwordx4 %9,  %16, off offset:1152\n\t"
    "global_load_dwordx4 %10, %16, off offset:1280\n\t"
    "global_load_dwordx4 %11, %16, off offset:1408\n\t"
    "global_load_dwordx4 %12, %16, off offset:1536\n\t"
    "global_load_dwordx4 %13, %16, off offset:1664\n\t"
    "global_load_dwordx4 %14, %16, off offset:1792\n\t"
    "global_load_dwordx4 %15, %16, off offset:1920"
    : "=&v"(a[0]), "=&v"(a[1]), "=&v"(a[2]), "=&v"(a[3]),
      "=&v"(a[4]), "=&v"(a[5]), "=&v"(a[6]), "=&v"(a[7]),
      "=&v"(a[8]), "=&v"(a[9]), "=&v"(a[10]), "=&v"(a[11]),
      "=&v"(a[12]), "=&v"(a[13]), "=&v"(a[14]), "=&v"(a[15])
    : "v"(p)
    : "memory");
}

__global__ void __launch_bounds__(256, 1) lmgru_kernel(
    const float* __restrict__ x,
    const float* __restrict__ Wz, const float* __restrict__ bz,
    const float* __restrict__ Wr, const float* __restrict__ br,
    const float* __restrict__ Wc, const float* __restrict__ bc,
    const float* __restrict__ Wo, const float* __restrict__ bo,
    const float* __restrict__ fcw, const float* __restrict__ fcb,
    float* __restrict__ out, char* __restrict__ ws)
{
  extern __shared__ char lds[];
  const int tid  = threadIdx.x;
  const int wg   = blockIdx.x;
  const int lane = tid & 63;
  const int q    = tid >> 6;          // wave id 0..3 == M-tile

  // ---- workspace layout ----
  unsigned short* hbuf  = (unsigned short*)ws;               // [2][64][1024] bf16
  unsigned short* rcbuf = (unsigned short*)(ws + 262144);    // [2][64][1024] bf16
  float*          h32   = (float*)(ws + 655360);             // [64][1024] f32
  int* hflag  = (int*)(ws + 524288);   // 128 flags, 64B apart
  int* rcflag = hflag + 2048;          // 128 flags, 64B apart

  float* zbuf = (float*)(lds + ZBUF_OFF);
  float* obuf = (float*)(lds + OBUF_OFF);
  float* xcb  = (float*)(lds + XCB_OFF);
  float* cst  = (float*)(lds + CST_OFF);
  float* rcs  = (float*)(lds + RCS_OFF);
  float* hst  = (float*)(lds + HST_OFF);
  float* bias = (float*)(lds + BIAS_OFF);

  const float* Wg[4] = {Wz, Wr, Wo, Wc};   // n-row layout: [z8 r8 o8 c8]

  // ================= INIT: build fragment-ordered bf16 weights in LDS =================
  for (int it = 0; it < 12; ++it) {
    int slot = tid + 256 * it;               // 3072 slots
    int s = slot >> 6, l = slot & 63;
    int nn = l & 15, kg = (l >> 4) & 3;
    int k = 32 * s + kg * 8;
    int g = (nn < 8) ? 0 : 1;
    const float* src = Wg[g] + (8 * wg + (nn & 7)) * 1536 + k;
    short8 pk;
    #pragma unroll
    for (int j = 0; j < 8; ++j) pk[j] = (short)f2bf(src[j]);
    *(short8*)(lds + T0_OFF + s * 1024 + l * 16) = pk;
  }
  for (int it = 0; it < 12; ++it) {
    int slot = tid + 256 * it;
    int s = slot >> 6, l = slot & 63;
    int nn = l & 15, kg = (l >> 4) & 3;
    int k = 32 * s + kg * 8;
    int g = (nn < 8) ? 2 : 3;
    short8 pk = {};
    if (g == 2 || k < 512) {
      const float* src = Wg[g] + (8 * wg + (nn & 7)) * 1536 + k;
      #pragma unroll
      for (int j = 0; j < 8; ++j) pk[j] = (short)f2bf(src[j]);
    }
    *(short8*)(lds + T1_OFF + s * 1024 + l * 16) = pk;
  }
  for (int it = 0; it < 8; ++it) {
    int slot = tid + 256 * it;               // 2048 slots
    int s = slot >> 6, l = slot & 63;
    int nn = l & 15, kg = (l >> 4) & 3;
    int k = 32 * s + kg * 8;                 // 0..1023
    short8 pk = {};
    if (nn < 8) {
      const float* src = Wc + (8 * wg + nn) * 1536 + 512 + k;
      #pragma unroll
      for (int j = 0; j < 8; ++j) pk[j] = (short)f2bf(src[j]);
    }
    *(short8*)(lds + T2_OFF + s * 1024 + l * 16) = pk;
  }
  if (tid < 32) {
    const float* Bg[4] = {bz, br, bo, bc};
    bias[tid] = Bg[tid >> 3][8 * wg + (tid & 7)];
  }
  for (int i2 = tid; i2 < 8 * PAD; i2 += 256) cst[i2] = 0.f;   // c state = 0
  if (tid < 64) {                            // h_0 = 0 (parity 0) -- coherent
    short8 z8 = {};
    cstore16(hbuf + tid * 1024 + 8 * wg, z8);
  }
  __syncthreads();
  if (tid == 0) {                            // flags: poison(negative) -> 0 releases init
    vmdrain();
    cstore4(hflag + wg * 16, 0);
    cstore4(rcflag + wg * 16, 0);
  }

  const int nn  = lane & 15;             // fragment col (output unit within tile)
  const int kg8 = ((lane >> 4) & 3) * 8; // A-frag k offset within kstep
  const int rbase = ((lane >> 4) & 3) * 4;
  const int brow  = 16 * q + nn;         // this thread's A-row (batch)
  const f32x4 zero4 = {0.f, 0.f, 0.f, 0.f};

  // ================= RECURRENCE: 2 sync rounds per step =================
  for (int t = 1; t <= TSTEPS; ++t) {
    const int pc = t & 1, pp = (t - 1) & 1;

    // ---------- PHASE 1: z, r, o preacts + Xc, all 64 batches ----------
    // issue x_t loads (read-only input, normal cached path) BEFORE the flag
    // wait: HBM/L2 latency hides under the straggler poll.
    f32x4 xa[16], xb[16];
    {
      const float* xp = x + brow * 262144 + (t - 1) * 512 + kg8;
      gload16_issue_s128(xp, xa);
      gload16_issue_s128(xp + 4, xb);
    }
    if (tid < 128) {
      const int* fp = hflag + tid * 16;
      while (cload4(fp) < t - 1) __builtin_amdgcn_s_sleep(1);
    }
    __syncthreads();
    vmdrain();                                // x data landed (pollers drained already)
    __builtin_amdgcn_sched_barrier(0);
    short8 axf[16];
    #pragma unroll
    for (int j = 0; j < 16; ++j) axf[j] = cvt8(xa[j], xb[j]);

    // gather h_{t-1} (coherent) and run x-part MFMAs while it flies
    f32x4 acc0a = zero4, acc0b = zero4, acc1a = zero4, acc1b = zero4;
    const unsigned short* hb = hbuf + pp * 65536 + brow * 1024;
    short8 ah0[16], ah1[16];
    cload16_issue(hb + kg8, ah0);
    cload16_issue(hb + 512 + kg8, ah1);
    #pragma unroll
    for (int j = 0; j < 16; ++j) {            // s = j : x ksteps
      short8 b0 = *(const short8*)(lds + T0_OFF + j * 1024 + lane * 16);
      short8 b1 = *(const short8*)(lds + T1_OFF + j * 1024 + lane * 16);
      f32x4& A0 = (j & 1) ? acc0b : acc0a;
      f32x4& A1 = (j & 1) ? acc1b : acc1a;
      A0 = __builtin_amdgcn_mfma_f32_16x16x32_bf16(axf[j], b0, A0, 0, 0, 0);
      A1 = __builtin_amdgcn_mfma_f32_16x16x32_bf16(axf[j], b1, A1, 0, 0, 0);
    }
    vmwait16();                               // ah0 (oldest 16) landed
    __builtin_amdgcn_sched_barrier(0);        // rule#18: no MFMA hoist past wait
    #pragma unroll
    for (int j = 0; j < 16; ++j) {            // s = 16+j : h[0:512]
      int s = 16 + j;
      short8 b0 = *(const short8*)(lds + T0_OFF + s * 1024 + lane * 16);
      short8 b1 = *(const short8*)(lds + T1_OFF + s * 1024 + lane * 16);
      f32x4& A0 = (j & 1) ? acc0b : acc0a;
      f32x4& A1 = (j & 1) ? acc1b : acc1a;
      A0 = __builtin_amdgcn_mfma_f32_16x16x32_bf16(ah0[j], b0, A0, 0, 0, 0);
      A1 = __builtin_amdgcn_mfma_f32_16x16x32_bf16(ah0[j], b1, A1, 0, 0, 0);
    }
    vmdrain();
    __builtin_amdgcn_sched_barrier(0);
    #pragma unroll
    for (int j = 0; j < 16; ++j) {            // s = 32+j : h[512:1024]
      int s = 32 + j;
      short8 b0 = *(const short8*)(lds + T0_OFF + s * 1024 + lane * 16);
      short8 b1 = *(const short8*)(lds + T1_OFF + s * 1024 + lane * 16);
      f32x4& A0 = (j & 1) ? acc0b : acc0a;
      f32x4& A1 = (j & 1) ? acc1b : acc1a;
      A0 = __builtin_amdgcn_mfma_f32_16x16x32_bf16(ah1[j], b0, A0, 0, 0, 0);
      A1 = __builtin_amdgcn_mfma_f32_16x16x32_bf16(ah1[j], b1, A1, 0, 0, 0);
    }
    {
      f32x4 acc0 = acc0a + acc0b, acc1 = acc1a + acc1b;
      #pragma unroll
      for (int i = 0; i < 4; ++i) {
        int b = 16 * q + rbase + i;
        float v0 = acc0[i] + bias[nn];        // z or r preact
        float v1 = acc1[i] + bias[16 + nn];   // o preact or Xc(+bias_c)
        if (nn < 8) {
          zbuf[nn * PAD + b] = sigm(v0);
          obuf[nn * PAD + b] = sigm(v1);
        } else {
          int u = nn - 8;
          rcs[u * PAD + b] = sigm(v0) * cst[u * PAD + b];  // r * c_{t-1}
          xcb[u * PAD + b] = v1;                            // Xc + bias_c
        }
      }
    }
    __syncthreads();
    if (tid < 64) {                            // wave 0: pack rc -> global + flag
      short8 pk;
      #pragma unroll
      for (int u = 0; u < 8; ++u) pk[u] = (short)f2bf(rcs[u * PAD + tid]);
      cstore16(rcbuf + pc * 65536 + tid * 1024 + 8 * wg, pk);
      vmdrain();                               // wave-level: covers all 64 lanes' stores
      if (tid == 0) cstore4(rcflag + wg * 16, t);
    }

    // ---------- PHASE 2: c_tilde, combine, publish h, all 64 batches ----------
    if (tid < 128) {
      const int* fp = rcflag + tid * 16;
      while (cload4(fp) < t) __builtin_amdgcn_s_sleep(1);
    }
    __syncthreads();

    f32x4 acca = zero4, accb = zero4;
    const unsigned short* rb = rcbuf + pc * 65536 + brow * 1024;
    short8 ar0[16], ar1[16];
    cload16_issue(rb + kg8, ar0);
    cload16_issue(rb + 512 + kg8, ar1);
    vmwait16();
    __builtin_amdgcn_sched_barrier(0);
    #pragma unroll
    for (int j = 0; j < 16; ++j) {
      short8 bf = *(const short8*)(lds + T2_OFF + j * 1024 + lane * 16);
      f32x4& A = (j & 1) ? accb : acca;
      A = __builtin_amdgcn_mfma_f32_16x16x32_bf16(ar0[j], bf, A, 0, 0, 0);
    }
    vmdrain();
    __builtin_amdgcn_sched_barrier(0);
    #pragma unroll
    for (int j = 0; j < 16; ++j) {
      int s = 16 + j;
      short8 bf = *(const short8*)(lds + T2_OFF + s * 1024 + lane * 16);
      f32x4& A = (j & 1) ? accb : acca;
      A = __builtin_amdgcn_mfma_f32_16x16x32_bf16(ar1[j], bf, A, 0, 0, 0);
    }
    if (nn < 8) {
      f32x4 acc = acca + accb;
      #pragma unroll
      for (int i = 0; i < 4; ++i) {
        int b = 16 * q + rbase + i;
        float ct = tanh_f(acc[i] + xcb[nn * PAD + b]);
        float z  = zbuf[nn * PAD + b];
        float cn = z * cst[nn * PAD + b] + (1.f - z) * ct;
        cst[nn * PAD + b] = cn;
        hst[nn * PAD + b] = obuf[nn * PAD + b] * tanh_f(cn);
      }
    }
    __syncthreads();
    if (tid < 64) {                            // wave 0: pack h -> global + flag
      if (t < TSTEPS) {
        short8 pk;
        #pragma unroll
        for (int u = 0; u < 8; ++u) pk[u] = (short)f2bf(hst[u * PAD + tid]);
        cstore16(hbuf + pc * 65536 + tid * 1024 + 8 * wg, pk);
        vmdrain();
        if (tid == 0) cstore4(hflag + wg * 16, t);
      } else {
        #pragma unroll
        for (int u = 0; u < 8; ++u) h32[tid * 1024 + 8 * wg + u] = hst[u * PAD + tid];
        if (tid == 0)
          __hip_atomic_store(hflag + wg * 16, t, __ATOMIC_RELEASE, __HIP_MEMORY_SCOPE_AGENT);
      }
    }
  }

  // ================= FINAL FC: out = h_T @ fc_w^T + fc_b =================
  if (tid < 128) {
    while (__hip_atomic_load(hflag + tid * 16, __ATOMIC_RELAXED, __HIP_MEMORY_SCOPE_AGENT) < TSTEPS)
      __builtin_amdgcn_s_sleep(1);
  }
  __syncthreads();
  __builtin_amdgcn_fence(__ATOMIC_ACQUIRE, "agent");   // one L2 inv, one-time

  if (wg < 125) {                                // 125 WGs * 8 classes = 1000
    for (int cc = 0; cc < 2; ++cc) {
      int c = 8 * wg + 2 * q + cc;
      const float* wrow = fcw + c * 1024;
      for (int b = 0; b < 64; ++b) {
        const float* hrow = h32 + b * 1024;
        float s = 0.f;
        for (int kk = lane; kk < 1024; kk += 64) s = __builtin_fmaf(hrow[kk], wrow[kk], s);
        #pragma unroll
        for (int off = 32; off; off >>= 1) s += __shfl_xor(s, off);
        if (lane == 0) out[b * 1000 + c] = s + fcb[c];
      }
    }
  }
}

extern "C" void kernel_launch(void* const* d_in, const int* in_sizes, int n_in,
                              void* d_out, int out_size, void* d_ws, size_t ws_size,
                              hipStream_t stream) {
  (void)in_sizes; (void)n_in; (void)out_size; (void)ws_size;
  const float* x   = (const float*)d_in[0];
  const float* Wz  = (const float*)d_in[1];
  const float* bz  = (const float*)d_in[2];
  const float* Wr  = (const float*)d_in[3];
  const float* br  = (const float*)d_in[4];
  const float* Wc  = (const float*)d_in[5];
  const float* bc  = (const float*)d_in[6];
  const float* Wo  = (const float*)d_in[7];
  const float* bo  = (const float*)d_in[8];
  const float* fcw = (const float*)d_in[9];
  const float* fcb = (const float*)d_in[10];

  hipFuncSetAttribute((const void*)lmgru_kernel,
                      hipFuncAttributeMaxDynamicSharedMemorySize, LDS_BYTES);

  hipLaunchKernelGGL(lmgru_kernel, dim3(NWG), dim3(256), LDS_BYTES, stream,
                     x, Wz, bz, Wr, br, Wc, bc, Wo, bo, fcw, fcb,
                     (float*)d_out, (char*)d_ws);
}